// Round 4
// baseline (9512.208 us; speedup 1.0000x reference)
//
#include <hip/hip_runtime.h>
#include <cstdint>
#include <cstddef>

#define Bz 64
#define Td 100
#define Sd 400
#define Ed 512
#define Hd 1024
#define Kd 512
#define Vd 34

typedef __attribute__((ext_vector_type(8))) short short8v;
typedef __attribute__((ext_vector_type(8))) unsigned short ushort8v;
typedef __attribute__((ext_vector_type(4))) float floatx4;

__device__ __forceinline__ float sigmoidf_(float x) {
    return 1.0f / (1.0f + __expf(-x));
}
__device__ __forceinline__ float tanhf_(float x) {
    float e = __expf(-2.0f * fabsf(x));
    float r = (1.0f - e) / (1.0f + e);
    return copysignf(r, x);
}
__device__ __forceinline__ unsigned short f2bf(float x) {
    unsigned int u = __float_as_uint(x);
    unsigned int r = (u + 0x7fffu + ((u >> 16) & 1u)) >> 16;
    return (unsigned short)r;
}
__device__ __forceinline__ float bf2f(unsigned short h) {
    return __uint_as_float(((unsigned int)h) << 16);
}

// ---------------------------------------------------------------------------
// Pack fp32 array -> bf16 hi plane + bf16 lo plane (split-bf16).
// ---------------------------------------------------------------------------
__global__ __launch_bounds__(256) void pack_w_kernel(
    const float* __restrict__ w, unsigned short* __restrict__ hi,
    unsigned short* __restrict__ lo, int n4)
{
    int i = blockIdx.x * 256 + threadIdx.x;
    if (i >= n4) return;
    float4 v = ((const float4*)w)[i];
    float f[4] = {v.x, v.y, v.z, v.w};
    unsigned short h[4], l[4];
    #pragma unroll
    for (int e = 0; e < 4; ++e) {
        h[e] = f2bf(f[e]);
        l[e] = f2bf(f[e] - bf2f(h[e]));
    }
    ushort4 hv = {h[0], h[1], h[2], h[3]};
    ushort4 lv = {l[0], l[1], l[2], l[3]};
    ((ushort4*)hi)[i] = hv;
    ((ushort4*)lo)[i] = lv;
}

// ---------------------------------------------------------------------------
// Split-bf16 MFMA LSTM-cell GEMM. All activations pre-packed as bf16 hi/lo.
// gates[64][4096] = X[64x2048] . W^T, K split in 8 slices of 256.
// Grid 256 = nt(32) x ks(8). Block 512 thr = 8 waves (2 waves/SIMD).
// Wave w: mh = w>>2 (m-frags mh*32, +16); nw=(w&3)*32 (n-frags nA=nt*128+nw, nB=+16).
// Per 32-k step: 3 MFMAs per frag pair (xh*wh + xl*wh + xh*wl), 12 per wave.
// X staged in LDS hi/lo, row stride 264 ushorts.
// k layout (2048): mode0 [emb512|ctx512|h_prev1024], mode1 [h_in1024|h_prev1024]
// ks<4 -> w_ih col (ks&3)*256 ; ks>=4 -> w_hh col (ks&3)*256.
// ---------------------------------------------------------------------------
__global__ __launch_bounds__(512) void gemm_cell_mfma(
    const unsigned short* __restrict__ x_hi, const unsigned short* __restrict__ x_lo,
    const int* __restrict__ labels, int t,
    const unsigned short* __restrict__ ctx_hi, const unsigned short* __restrict__ ctx_lo,
    const unsigned short* __restrict__ hp_hi, const unsigned short* __restrict__ hp_lo,
    const unsigned short* __restrict__ wih_hi, const unsigned short* __restrict__ wih_lo,
    const unsigned short* __restrict__ whh_hi, const unsigned short* __restrict__ whh_lo,
    float* __restrict__ gpart, int mode)
{
    __shared__ unsigned short xs[64 * 264];
    const int tid  = threadIdx.x;
    const int w    = tid >> 6;
    const int lane = tid & 63;
    const int quad = lane >> 4;
    const int l16  = lane & 15;
    const int nt   = blockIdx.x & 31;
    const int ks   = blockIdx.x >> 5;     // 0..7
    const int mh   = w >> 2;              // 0/1
    const int nA   = nt * 128 + (w & 3) * 32;
    const int nB   = nA + 16;

    const unsigned short* whi = (ks < 4) ? wih_hi : whh_hi;
    const unsigned short* wlo = (ks < 4) ? wih_lo : whh_lo;
    const int kcol0 = (ks & 3) * 256;

    floatx4 zero = {0.f, 0.f, 0.f, 0.f};
    floatx4 accA[2] = {zero, zero};   // (mf, nA)
    floatx4 accB[2] = {zero, zero};   // (mf, nB)

    for (int kc = 0; kc < 2; ++kc) {
        __syncthreads();
        // ---- stage 64 rows x 128 k of pre-packed hi/lo: 1024 groups, 2/thread ----
        #pragma unroll
        for (int it = 0; it < 2; ++it) {
            int p = it * 512 + tid;      // 0..1023 = row(64) x group(16)
            int r = p >> 4;
            int g = p & 15;
            int kg = kcol0 + kc * 128 + g * 8;
            const unsigned short *shi, *slo;
            size_t idx;
            if (mode == 0) {
                if (ks < 2)      { idx = (size_t)labels[r * Td + t] * Ed + kg; shi = x_hi;  slo = x_lo; }
                else if (ks < 4) { idx = (size_t)r * Kd + (kg - 512);          shi = ctx_hi; slo = ctx_lo; }
                else             { idx = (size_t)r * Hd + kg;                  shi = hp_hi; slo = hp_lo; }
            } else {
                if (ks < 4)      { idx = (size_t)r * Hd + kg;                  shi = x_hi;  slo = x_lo; }
                else             { idx = (size_t)r * Hd + kg;                  shi = hp_hi; slo = hp_lo; }
            }
            ushort8v H = *(const ushort8v*)(shi + idx);
            ushort8v L = *(const ushort8v*)(slo + idx);
            unsigned short* dst = xs + r * 264 + g * 16;
            *(ushort8v*)dst       = H;
            *(ushort8v*)(dst + 8) = L;
        }
        __syncthreads();

        // ---- 4 k-steps of 32, 1-step weight prefetch ----
        int kcol = kcol0 + kc * 128 + quad * 8;
        size_t rA = ((size_t)(nA + l16)) * 1024 + kcol;
        size_t rB = ((size_t)(nB + l16)) * 1024 + kcol;
        short8v bAh = *(const short8v*)(whi + rA);
        short8v bAl = *(const short8v*)(wlo + rA);
        short8v bBh = *(const short8v*)(whi + rB);
        short8v bBl = *(const short8v*)(wlo + rB);
        #pragma unroll
        for (int kk = 0; kk < 4; ++kk) {
            short8v cAh = bAh, cAl = bAl, cBh = bBh, cBl = bBl;
            if (kk < 3) {
                bAh = *(const short8v*)(whi + rA + 32 * (kk + 1));
                bAl = *(const short8v*)(wlo + rA + 32 * (kk + 1));
                bBh = *(const short8v*)(whi + rB + 32 * (kk + 1));
                bBl = *(const short8v*)(wlo + rB + 32 * (kk + 1));
            }
            #pragma unroll
            for (int mf = 0; mf < 2; ++mf) {
                const unsigned short* ar = xs + (mh * 32 + mf * 16 + l16) * 264 + (kk * 4 + quad) * 16;
                short8v ah = *(const short8v*)ar;
                short8v al = *(const short8v*)(ar + 8);
                accA[mf] = __builtin_amdgcn_mfma_f32_16x16x32_bf16(ah, cAh, accA[mf], 0, 0, 0);
                accA[mf] = __builtin_amdgcn_mfma_f32_16x16x32_bf16(al, cAh, accA[mf], 0, 0, 0);
                accA[mf] = __builtin_amdgcn_mfma_f32_16x16x32_bf16(ah, cAl, accA[mf], 0, 0, 0);
                accB[mf] = __builtin_amdgcn_mfma_f32_16x16x32_bf16(ah, cBh, accB[mf], 0, 0, 0);
                accB[mf] = __builtin_amdgcn_mfma_f32_16x16x32_bf16(al, cBh, accB[mf], 0, 0, 0);
                accB[mf] = __builtin_amdgcn_mfma_f32_16x16x32_bf16(ah, cBl, accB[mf], 0, 0, 0);
            }
        }
    }

    // ---- epilogue: D row(m) = quad*4+reg, col(n) = l16 ----
    #pragma unroll
    for (int mf = 0; mf < 2; ++mf) {
        int m = mh * 32 + mf * 16 + quad * 4;
        float* gA = gpart + ((size_t)ks * 64 + m) * 4096 + nA + l16;
        float* gB = gpart + ((size_t)ks * 64 + m) * 4096 + nB + l16;
        #pragma unroll
        for (int reg = 0; reg < 4; ++reg) {
            gA[(size_t)reg * 4096] = accA[mf][reg];
            gB[(size_t)reg * 4096] = accB[mf][reg];
        }
    }
}

// ---------------------------------------------------------------------------
// Fallback split-K fp32 LSTM-cell GEMM (used if ws too small).
// ---------------------------------------------------------------------------
__global__ __launch_bounds__(256) void gemm_cell(
    const float* __restrict__ src0,
    const int* __restrict__ labels, int t,
    const float* __restrict__ ctx,
    const float* __restrict__ h_prev,
    const float* __restrict__ w_ih, const float* __restrict__ w_hh,
    float* __restrict__ gpart, int mode)
{
    __shared__ float lds[32 * 132];
    const int tid = threadIdx.x;
    const int bq  = tid & 15;
    const int jl  = tid >> 4;
    const int bid = blockIdx.x;
    const int jg  = bid & 63;
    const int ks  = (bid >> 6) & 3;
    const int bh  = bid >> 8;
    const int j   = jg * 16 + jl;
    const int b0  = bh * 32;

    const float* wsrc = (ks < 2) ? w_ih : w_hh;
    const int koff = (ks & 1) * 512;
    const float* w0 = wsrc + ((size_t)j)          * 1024 + koff;
    const float* w1 = wsrc + ((size_t)(1024 + j)) * 1024 + koff;
    const float* w2 = wsrc + ((size_t)(2048 + j)) * 1024 + koff;
    const float* w3 = wsrc + ((size_t)(3072 + j)) * 1024 + koff;

    float acc00 = 0.f, acc01 = 0.f, acc02 = 0.f, acc03 = 0.f;
    float acc10 = 0.f, acc11 = 0.f, acc12 = 0.f, acc13 = 0.f;

    for (int sub = 0; sub < 4; ++sub) {
        __syncthreads();
        #pragma unroll
        for (int it = 0; it < 4; ++it) {
            int idx = (it << 8) + tid;
            int r   = idx >> 5;
            int c4  = (idx & 31) << 2;
            int b   = b0 + r;
            const float* src;
            if (mode == 0) {
                if (ks == 0)      src = src0 + (size_t)labels[b * Td + t] * Ed + (sub << 7) + c4;
                else if (ks == 1) src = ctx + b * Kd + (sub << 7) + c4;
                else              src = h_prev + b * Hd + ((ks - 2) << 9) + (sub << 7) + c4;
            } else {
                if (ks < 2)       src = src0 + b * Hd + (ks << 9) + (sub << 7) + c4;
                else              src = h_prev + b * Hd + ((ks - 2) << 9) + (sub << 7) + c4;
            }
            float4 v = *(const float4*)src;
            float* d = lds + r * 132 + c4;
            d[0] = v.x; d[1] = v.y; d[2] = v.z; d[3] = v.w;
        }
        __syncthreads();

        const float* wp0 = w0 + (sub << 7);
        const float* wp1 = w1 + (sub << 7);
        const float* wp2 = w2 + (sub << 7);
        const float* wp3 = w3 + (sub << 7);
        const float* l0  = lds + bq * 132;
        const float* l1  = lds + (bq + 16) * 132;
        #pragma unroll 4
        for (int k4 = 0; k4 < 32; ++k4) {
            float4 wv0 = *(const float4*)(wp0 + (k4 << 2));
            float4 wv1 = *(const float4*)(wp1 + (k4 << 2));
            float4 wv2 = *(const float4*)(wp2 + (k4 << 2));
            float4 wv3 = *(const float4*)(wp3 + (k4 << 2));
            float4 a0  = *(const float4*)(l0 + (k4 << 2));
            float4 a1  = *(const float4*)(l1 + (k4 << 2));
            acc00 += a0.x*wv0.x; acc00 += a0.y*wv0.y; acc00 += a0.z*wv0.z; acc00 += a0.w*wv0.w;
            acc01 += a0.x*wv1.x; acc01 += a0.y*wv1.y; acc01 += a0.z*wv1.z; acc01 += a0.w*wv1.w;
            acc02 += a0.x*wv2.x; acc02 += a0.y*wv2.y; acc02 += a0.z*wv2.z; acc02 += a0.w*wv2.w;
            acc03 += a0.x*wv3.x; acc03 += a0.y*wv3.y; acc03 += a0.z*wv3.z; acc03 += a0.w*wv3.w;
            acc10 += a1.x*wv0.x; acc10 += a1.y*wv0.y; acc10 += a1.z*wv0.z; acc10 += a1.w*wv0.w;
            acc11 += a1.x*wv1.x; acc11 += a1.y*wv1.y; acc11 += a1.z*wv1.z; acc11 += a1.w*wv1.w;
            acc12 += a1.x*wv2.x; acc12 += a1.y*wv2.y; acc12 += a1.z*wv2.z; acc12 += a1.w*wv2.w;
            acc13 += a1.x*wv3.x; acc13 += a1.y*wv3.y; acc13 += a1.z*wv3.z; acc13 += a1.w*wv3.w;
        }
    }

    const size_t rowA = ((size_t)ks * 64 + b0 + bq) * 4096;
    const size_t rowB = ((size_t)ks * 64 + b0 + bq + 16) * 4096;
    gpart[rowA + 0 * 1024 + j] = acc00;
    gpart[rowA + 1 * 1024 + j] = acc01;
    gpart[rowA + 2 * 1024 + j] = acc02;
    gpart[rowA + 3 * 1024 + j] = acc03;
    gpart[rowB + 0 * 1024 + j] = acc10;
    gpart[rowB + 1 * 1024 + j] = acc11;
    gpart[rowB + 2 * 1024 + j] = acc12;
    gpart[rowB + 3 * 1024 + j] = acc13;
}

// ---------------------------------------------------------------------------
// Sum nsl k-slice partials + biases, LSTM pointwise, write h (fp32 + hi/lo) and c.
// ---------------------------------------------------------------------------
__global__ __launch_bounds__(256) void combine_cell(
    const float* __restrict__ gpart,
    const float* __restrict__ b_ih, const float* __restrict__ b_hh,
    float* c, float* __restrict__ h,
    unsigned short* __restrict__ h_hi, unsigned short* __restrict__ h_lo, int nsl)
{
    int el = blockIdx.x * 256 + threadIdx.x;
    int b = el >> 10, j = el & 1023;
    float g[4];
    #pragma unroll
    for (int gi = 0; gi < 4; ++gi)
        g[gi] = b_ih[gi * 1024 + j] + b_hh[gi * 1024 + j];
    for (int ksi = 0; ksi < nsl; ++ksi) {
        const float* row = gpart + ((size_t)ksi * 64 + b) * 4096 + j;
        #pragma unroll
        for (int gi = 0; gi < 4; ++gi)
            g[gi] += row[gi * 1024];
    }
    float ig = sigmoidf_(g[0]);
    float fg = sigmoidf_(g[1]);
    float gg = tanhf_(g[2]);
    float og = sigmoidf_(g[3]);
    float cn = fg * c[el] + ig * gg;
    c[el] = cn;
    float hv = og * tanhf_(cn);
    h[el] = hv;
    if (h_hi) {
        unsigned short hh = f2bf(hv);
        h_hi[el] = hh;
        h_lo[el] = f2bf(hv - bf2f(hh));
    }
}

// ---------------------------------------------------------------------------
// q partial GEMM: qpart[ks][b][n] over k-slice of 256 (fp32 vector).
// ---------------------------------------------------------------------------
__global__ __launch_bounds__(256) void gemm_q(
    const float* __restrict__ h3, const float* __restrict__ w_proj,
    float* __restrict__ qpart)
{
    __shared__ float lds[32 * 132];
    const int tid = threadIdx.x;
    const int bq = tid & 15, nl = tid >> 4;
    const int bid = blockIdx.x;
    const int ng = bid & 31, ks = (bid >> 5) & 3, bh = bid >> 7;
    const int n = ng * 16 + nl;
    const int b0 = bh * 32;
    const float* wp = w_proj + (size_t)n * 1024 + (ks << 8);

    float acc0 = 0.f, acc1 = 0.f;
    for (int sub = 0; sub < 2; ++sub) {
        __syncthreads();
        #pragma unroll
        for (int it = 0; it < 4; ++it) {
            int idx = (it << 8) + tid;
            int r = idx >> 5, c4 = (idx & 31) << 2;
            float4 v = *(const float4*)(h3 + (size_t)(b0 + r) * 1024 + (ks << 8) + (sub << 7) + c4);
            float* d = lds + r * 132 + c4;
            d[0] = v.x; d[1] = v.y; d[2] = v.z; d[3] = v.w;
        }
        __syncthreads();
        const float* l0 = lds + bq * 132;
        const float* l1 = lds + (bq + 16) * 132;
        const float* wq = wp + (sub << 7);
        #pragma unroll 4
        for (int k4 = 0; k4 < 32; ++k4) {
            float4 wv = *(const float4*)(wq + (k4 << 2));
            float4 a0 = *(const float4*)(l0 + (k4 << 2));
            float4 a1 = *(const float4*)(l1 + (k4 << 2));
            acc0 += a0.x*wv.x; acc0 += a0.y*wv.y; acc0 += a0.z*wv.z; acc0 += a0.w*wv.w;
            acc1 += a1.x*wv.x; acc1 += a1.y*wv.y; acc1 += a1.z*wv.z; acc1 += a1.w*wv.w;
        }
    }
    qpart[((size_t)ks * 64 + b0 + bq) * 512 + n]      = acc0;
    qpart[((size_t)ks * 64 + b0 + bq + 16) * 512 + n] = acc1;
}

// ---------------------------------------------------------------------------
// Energy + online-softmax partials + weighted value partial sums.
// Grid 512 = 64 b x 8 s-chunks (50 s each).
// ---------------------------------------------------------------------------
__global__ __launch_bounds__(256) void energy_kernel(
    const float* __restrict__ qpart, const float* __restrict__ b_proj,
    const float* __restrict__ keys, const float* __restrict__ values,
    float* __restrict__ attn, int t,
    float* __restrict__ u_part, float* __restrict__ m_part, float* __restrict__ z_part)
{
    __shared__ float qs[4 * 132];
    __shared__ float es[64];
    __shared__ float ps[64];
    __shared__ float mz[1];
    const int tid = threadIdx.x;
    const int b   = blockIdx.x >> 3;
    const int ch  = blockIdx.x & 7;

    for (int k = tid; k < 512; k += 256) {
        float s = b_proj[k];
        #pragma unroll
        for (int ksi = 0; ksi < 4; ++ksi)
            s += qpart[((size_t)ksi * 64 + b) * 512 + k];
        qs[(k >> 7) * 132 + (k & 127)] = s;
    }
    __syncthreads();

    if (tid < 200) {
        int sl = tid >> 2, part = tid & 3;
        int s = ch * 50 + sl;
        const float* kr = keys + ((size_t)s * Bz + b) * Kd + part * 128;
        const float* qp = qs + part * 132;
        float e = 0.f;
        #pragma unroll 8
        for (int i4 = 0; i4 < 32; ++i4) {
            float4 kv = *(const float4*)(kr + (i4 << 2));
            e += qp[(i4 << 2) + 0] * kv.x;
            e += qp[(i4 << 2) + 1] * kv.y;
            e += qp[(i4 << 2) + 2] * kv.z;
            e += qp[(i4 << 2) + 3] * kv.w;
        }
        e += __shfl_down(e, 1);
        e += __shfl_down(e, 2);
        if (part == 0) es[sl] = e;
    }
    __syncthreads();
    if (tid == 0) {
        float m = -1e30f;
        for (int i = 0; i < 50; ++i) m = fmaxf(m, es[i]);
        mz[0] = m;
    }
    __syncthreads();
    float m = mz[0];
    if (tid < 50) {
        float p = __expf(es[tid] - m);
        ps[tid] = p;
        attn[(size_t)b * (Td * Sd) + t * Sd + ch * 50 + tid] = p;  // unnormalized
    }
    __syncthreads();
    if (tid == 0) {
        float z = 0.f;
        for (int i = 0; i < 50; ++i) z += ps[i];
        m_part[b * 8 + ch] = m;
        z_part[b * 8 + ch] = z;
    }
    float u0 = 0.f, u1 = 0.f;
    const float* vbase = values + ((size_t)(ch * 50) * Bz + b) * Kd;
    for (int s = 0; s < 50; ++s) {
        const float* vr = vbase + (size_t)s * Bz * Kd;
        float p = ps[s];
        u0 += p * vr[tid];
        u1 += p * vr[tid + 256];
    }
    u_part[((b << 3) + ch) * 512 + tid]       = u0;
    u_part[((b << 3) + ch) * 512 + tid + 256] = u1;
}

// ---------------------------------------------------------------------------
// Combine softmax partials -> ctx (fp32 + hi/lo); normalize attn row; score.
// ---------------------------------------------------------------------------
__global__ __launch_bounds__(256) void finalize_kernel(
    const float* __restrict__ qpart, const float* __restrict__ b_proj,
    const float* __restrict__ u_part,
    const float* __restrict__ m_part, const float* __restrict__ z_part,
    float* __restrict__ ctx,
    unsigned short* __restrict__ ctx_hi, unsigned short* __restrict__ ctx_lo,
    float* __restrict__ attn, float* __restrict__ pred,
    const float* __restrict__ w_score, const float* __restrict__ b_score, int t)
{
    __shared__ float fc[8];
    __shared__ float qs[512];
    __shared__ float cs[512];
    const int tid = threadIdx.x;
    const int b = blockIdx.x;

    if (tid == 0) {
        float M = -1e30f;
        for (int c = 0; c < 8; ++c) M = fmaxf(M, m_part[b * 8 + c]);
        float f[8];
        float Z = 0.f;
        for (int c = 0; c < 8; ++c) {
            f[c] = __expf(m_part[b * 8 + c] - M);
            Z += z_part[b * 8 + c] * f[c];
        }
        float inv = 1.0f / Z;
        for (int c = 0; c < 8; ++c) fc[c] = f[c] * inv;
    }
    __syncthreads();

    for (int k = tid; k < 512; k += 256) {
        float s = b_proj[k];
        #pragma unroll
        for (int ksi = 0; ksi < 4; ++ksi)
            s += qpart[((size_t)ksi * 64 + b) * 512 + k];
        qs[k] = s;
        float acc = 0.f;
        #pragma unroll
        for (int c = 0; c < 8; ++c)
            acc += u_part[((b << 3) + c) * 512 + k] * fc[c];
        ctx[b * Kd + k] = acc;
        if (ctx_hi) {
            unsigned short hh = f2bf(acc);
            ctx_hi[b * Kd + k] = hh;
            ctx_lo[b * Kd + k] = f2bf(acc - bf2f(hh));
        }
        cs[k] = acc;
    }
    for (int s = tid; s < Sd; s += 256) {
        attn[(size_t)b * (Td * Sd) + t * Sd + s] *= fc[s / 50];
    }
    __syncthreads();

    if (tid < 136) {
        int v = tid >> 2, part = tid & 3;
        const float* wr = w_score + (size_t)v * 1024 + part * 256;
        const float* src = (part < 2) ? (qs + part * 256) : (cs + (part - 2) * 256);
        float acc = 0.f;
        #pragma unroll 8
        for (int i = 0; i < 256; ++i) acc += src[i] * wr[i];
        acc += __shfl_down(acc, 1);
        acc += __shfl_down(acc, 2);
        if (part == 0) pred[(size_t)b * (Td * Vd) + t * Vd + v] = acc + b_score[v];
    }
}

// ---------------------------------------------------------------------------
__global__ void init_states(const float* __restrict__ h0,
    float* h1, float* h2, float* h3, float* c1, float* c2, float* c3,
    unsigned short* h1h, unsigned short* h1l,
    unsigned short* h2h, unsigned short* h2l,
    unsigned short* h3h, unsigned short* h3l, int do_pack)
{
    int idx = blockIdx.x * 256 + threadIdx.x;
    int arr = idx >> 16;
    int off = idx & 65535;
    float v = h0[off & 1023];
    float* p;
    switch (arr) {
        case 0: p = h1; break;
        case 1: p = h2; break;
        case 2: p = h3; break;
        case 3: p = c1; break;
        case 4: p = c2; break;
        default: p = c3; break;
    }
    p[off] = v;
    if (do_pack && arr < 3) {
        unsigned short* ph = (arr == 0) ? h1h : (arr == 1) ? h2h : h3h;
        unsigned short* pl = (arr == 0) ? h1l : (arr == 1) ? h2l : h3l;
        unsigned short hh = f2bf(v);
        ph[off] = hh;
        pl[off] = f2bf(v - bf2f(hh));
    }
}

__global__ void init_ctx(const float* __restrict__ h0, const float* __restrict__ w_proj,
                         const float* __restrict__ b_proj, float* __restrict__ ctx,
                         unsigned short* ctx_hi, unsigned short* ctx_lo, int do_pack)
{
    int k = blockIdx.x * 256 + threadIdx.x;
    float acc = b_proj[k];
    const float* wr = w_proj + (size_t)k * 1024;
    for (int j = 0; j < 1024; ++j) acc += h0[j] * wr[j];
    unsigned short hh = f2bf(acc);
    unsigned short ll = f2bf(acc - bf2f(hh));
    for (int b = 0; b < Bz; ++b) {
        ctx[b * Kd + k] = acc;
        if (do_pack) { ctx_hi[b * Kd + k] = hh; ctx_lo[b * Kd + k] = ll; }
    }
}

// ---------------------------------------------------------------------------
extern "C" void kernel_launch(void* const* d_in, const int* in_sizes, int n_in,
                              void* d_out, int out_size, void* d_ws, size_t ws_size,
                              hipStream_t stream)
{
    (void)in_sizes; (void)n_in; (void)out_size;
    const int*   labels = (const int*)d_in[0];
    const float* keys   = (const float*)d_in[1];
    const float* values = (const float*)d_in[2];
    const float* emb    = (const float*)d_in[3];
    const float* w_ih0  = (const float*)d_in[4];
    const float* w_hh0  = (const float*)d_in[5];
    const float* b_ih0  = (const float*)d_in[6];
    const float* b_hh0  = (const float*)d_in[7];
    const float* w_ih1  = (const float*)d_in[8];
    const float* w_hh1  = (const float*)d_in[9];
    const float* b_ih1  = (const float*)d_in[10];
    const float* b_hh1  = (const float*)d_in[11];
    const float* w_ih2  = (const float*)d_in[12];
    const float* w_hh2  = (const float*)d_in[13];
    const float* b_ih2  = (const float*)d_in[14];
    const float* b_hh2  = (const float*)d_in[15];
    const float* w_proj = (const float*)d_in[16];
    const float* b_proj = (const float*)d_in[17];
    const float* w_score= (const float*)d_in[18];
    const float* b_score= (const float*)d_in[19];
    const float* h0     = (const float*)d_in[20];

    float* ws = (float*)d_ws;
    float* h1 = ws + 0;
    float* h2 = ws + 65536;
    float* h3 = ws + 131072;
    float* c1 = ws + 196608;
    float* c2 = ws + 262144;
    float* c3 = ws + 327680;
    float* ctx = ws + 393216;     // 64x512
    float* gpart = ws + 425984;   // up to 8 x 64 x 4096
    float* qpart = ws + 2523136;  // 4 x 64 x 512
    float* u_part = ws + 2654208; // 64 x 8 x 512
    float* m_part = ws + 2916352; // 512
    float* z_part = ws + 2916864; // 512

    // ushort region: 12 weight planes + h/ctx/emb activation planes
    unsigned short* us_base = (unsigned short*)(ws + 2917376);
    const size_t PLANE = (size_t)4096 * 1024;           // ushorts per weight plane
    unsigned short* Whi[3][2]; unsigned short* Wlo[3][2];
    const float* Wsrc[3][2] = {{w_ih0, w_hh0}, {w_ih1, w_hh1}, {w_ih2, w_hh2}};
    for (int c = 0; c < 3; ++c)
        for (int p = 0; p < 2; ++p) {
            Whi[c][p] = us_base + ((size_t)(c * 2 + p) * 2 + 0) * PLANE;
            Wlo[c][p] = us_base + ((size_t)(c * 2 + p) * 2 + 1) * PLANE;
        }
    unsigned short* act = us_base + 12 * PLANE;
    unsigned short* h1h = act;            unsigned short* h1l = act + 65536;
    unsigned short* h2h = act + 131072;   unsigned short* h2l = act + 196608;
    unsigned short* h3h = act + 262144;   unsigned short* h3l = act + 327680;
    unsigned short* ctxh = act + 393216;  unsigned short* ctxl = act + 425984;
    unsigned short* embh = act + 458752;  unsigned short* embl = act + 476160;
    const size_t US_TOTAL = 12 * PLANE + 458752 + 2 * 17408;
    const size_t NEED = (size_t)2917376 * 4 + US_TOTAL * 2;
    const bool fast = (ws_size >= NEED);

    float* pred = (float*)d_out;                        // [B,T,V]
    float* attn = (float*)d_out + (size_t)Bz * Td * Vd; // [B,T,S]

    if (fast) {
        const int n4 = (int)(PLANE / 4);
        for (int c = 0; c < 3; ++c)
            for (int p = 0; p < 2; ++p)
                pack_w_kernel<<<(n4 + 255) / 256, 256, 0, stream>>>(
                    Wsrc[c][p], Whi[c][p], Wlo[c][p], n4);
        pack_w_kernel<<<(4352 + 255) / 256, 256, 0, stream>>>(emb, embh, embl, 4352);
    }

    init_states<<<1536, 256, 0, stream>>>(h0, h1, h2, h3, c1, c2, c3,
                                          h1h, h1l, h2h, h2l, h3h, h3l, fast ? 1 : 0);
    init_ctx<<<2, 256, 0, stream>>>(h0, w_proj, b_proj, ctx, ctxh, ctxl, fast ? 1 : 0);

    const float* bih[3] = {b_ih0, b_ih1, b_ih2};
    const float* bhh[3] = {b_hh0, b_hh1, b_hh2};
    float* hs[3] = {h1, h2, h3};
    float* cs_[3] = {c1, c2, c3};
    unsigned short* hh_[3] = {h1h, h2h, h3h};
    unsigned short* hl_[3] = {h1l, h2l, h3l};

    for (int t = 0; t < Td; ++t) {
        for (int cell = 0; cell < 3; ++cell) {
            if (fast) {
                const unsigned short* xh = (cell == 0) ? embh : hh_[cell - 1];
                const unsigned short* xl = (cell == 0) ? embl : hl_[cell - 1];
                gemm_cell_mfma<<<256, 512, 0, stream>>>(
                    xh, xl, labels, t, ctxh, ctxl, hh_[cell], hl_[cell],
                    Whi[cell][0], Wlo[cell][0], Whi[cell][1], Wlo[cell][1],
                    gpart, (cell == 0) ? 0 : 1);
                combine_cell<<<256, 256, 0, stream>>>(gpart, bih[cell], bhh[cell],
                                                      cs_[cell], hs[cell],
                                                      hh_[cell], hl_[cell], 8);
            } else {
                const float* x = (cell == 0) ? emb : hs[cell - 1];
                gemm_cell<<<512, 256, 0, stream>>>(
                    x, labels, t, ctx, hs[cell],
                    Wsrc[cell][0], Wsrc[cell][1], gpart, (cell == 0) ? 0 : 1);
                combine_cell<<<256, 256, 0, stream>>>(gpart, bih[cell], bhh[cell],
                                                      cs_[cell], hs[cell],
                                                      nullptr, nullptr, 4);
            }
        }
        gemm_q<<<256, 256, 0, stream>>>(h3, w_proj, qpart);
        energy_kernel<<<512, 256, 0, stream>>>(qpart, b_proj, keys, values, attn, t,
                                               u_part, m_part, z_part);
        finalize_kernel<<<64, 256, 0, stream>>>(qpart, b_proj, u_part, m_part, z_part,
                                                ctx, fast ? ctxh : nullptr, fast ? ctxl : nullptr,
                                                attn, pred, w_score, b_score, t);
    }
}